// Round 4
// baseline (435.480 us; speedup 1.0000x reference)
//
#include <hip/hip_runtime.h>
#include <hip/hip_bf16.h>
#include <stdint.h>

typedef __bf16 bf16_t;
typedef __bf16 bf16x4 __attribute__((ext_vector_type(4)));
typedef __bf16 bf16x8 __attribute__((ext_vector_type(8)));
typedef short s16x4 __attribute__((ext_vector_type(4)));
typedef float f32x4 __attribute__((ext_vector_type(4)));

static_assert(sizeof(bf16x8) == 16, "bf16x8 must be 16B");

#define MFMA_BF16(a, b, c) __builtin_amdgcn_mfma_f32_16x16x32_bf16((a), (b), (c), 0, 0, 0)

// 16x16x16 bf16 MFMA (A[m=l15][k=quad*4+i], B[k=quad*4+i][n=l15],
// C/D row=quad*4+r col=l15)
__device__ __forceinline__ f32x4 mfma16(bf16x4 a, bf16x4 b, f32x4 c) {
#if __has_builtin(__builtin_amdgcn_mfma_f32_16x16x16bf16_1k)
  union { bf16x4 h; s16x4 s; } ua, ub;
  ua.h = a;
  ub.h = b;
  return __builtin_amdgcn_mfma_f32_16x16x16bf16_1k(ua.s, ub.s, c, 0, 0, 0);
#else
  f32x4 d = c;
  asm volatile("v_mfma_f32_16x16x16_bf16 %0, %1, %2, %0" : "+v"(d) : "v"(a), "v"(b));
  return d;
#endif
}

typedef const __attribute__((address_space(1))) void* gas_ptr;
typedef __attribute__((address_space(3))) void* las_ptr;

__device__ __forceinline__ void gload_lds16(const void* g, void* l) {
  __builtin_amdgcn_global_load_lds((gas_ptr)g, (las_ptr)l, 16, 0, 0);
}

// compile-time memory-op ordering fence (pins global_load_lds issue order)
#define ORDER_FENCE() asm volatile("" ::: "memory")

#define NEG_BIG (-1.0e30f)

// ---------------------------------------------------------------------------
// fp32 -> bf16 convert, all three inputs in one launch.
// ranges (floats): x [0, 8388608) | wq [8388608, 9175040) | wp [9175040, 9437184)
// ---------------------------------------------------------------------------
__global__ __launch_bounds__(256) void cvt3_kernel(
    const float* __restrict__ x, const float* __restrict__ wq,
    const float* __restrict__ wp, bf16_t* __restrict__ xb,
    bf16_t* __restrict__ wqb, bf16_t* __restrict__ wpb) {
  const int i = (blockIdx.x * 256 + threadIdx.x) * 4;
  const float* src;
  bf16_t* dst;
  int off;
  if (i < 8388608) {
    src = x; dst = xb; off = 0;
  } else if (i < 9175040) {
    src = wq; dst = wqb; off = 8388608;
  } else {
    src = wp; dst = wpb; off = 9175040;
  }
  const f32x4 v = *(const f32x4*)(src + (i - off));
  bf16x4 o;
  o[0] = (bf16_t)v[0];
  o[1] = (bf16_t)v[1];
  o[2] = (bf16_t)v[2];
  o[3] = (bf16_t)v[3];
  *(bf16x4*)(dst + (i - off)) = o;
}

// ---------------------------------------------------------------------------
// GEMM (m97 structure): D[m][n] = sum_k A[m][k] * Bw[n][k]
// MODE 0: qkv epilogue -> q / k row-major (bf16), v transposed to vT[b][d][t]
// MODE 1: final epilogue -> o_f as FP32
// ---------------------------------------------------------------------------
template <int MODE>
__global__ __launch_bounds__(256, 2) void gemm_bt_kernel(
    const bf16_t* __restrict__ A, const bf16_t* __restrict__ Bw,
    bf16_t* __restrict__ o_q, bf16_t* __restrict__ o_k, bf16_t* __restrict__ o_vT,
    float* __restrict__ o_f) {
  constexpr int K = 512;
  __shared__ bf16_t As[128 * 32];
  __shared__ bf16_t Bs[128 * 32];

  const int tid = threadIdx.x;
  const int lane = tid & 63;
  const int wid = tid >> 6;
  const int quad = lane >> 4;
  const int l15 = lane & 15;
  const int wm = wid >> 1;
  const int wn = wid & 1;

  const int mt = blockIdx.x & 127;
  const int nt = blockIdx.x >> 7;
  const int row0 = mt * 128;
  const int col0 = nt * 128;

  f32x4 acc[4][4] = {};

  for (int kt = 0; kt < K; kt += 32) {
    __syncthreads();
#pragma unroll
    for (int rnd = 0; rnd < 2; rnd++) {
      const int e = (rnd * 256 + tid) * 8;
      const int r = e >> 5;
      const int c = e & 31;
      gload_lds16(A + (size_t)(row0 + r) * K + kt + c, As + e);
      gload_lds16(Bw + (size_t)(col0 + r) * K + kt + c, Bs + e);
    }
    __syncthreads();

    bf16x8 af[4], bfr[4];
#pragma unroll
    for (int i = 0; i < 4; i++)
      af[i] = *(const bf16x8*)(As + (wm * 64 + i * 16 + l15) * 32 + quad * 8);
#pragma unroll
    for (int i = 0; i < 4; i++)
      bfr[i] = *(const bf16x8*)(Bs + (wn * 64 + i * 16 + l15) * 32 + quad * 8);
#pragma unroll
    for (int mi = 0; mi < 4; mi++)
#pragma unroll
      for (int ni = 0; ni < 4; ni++)
        acc[mi][ni] = MFMA_BF16(af[mi], bfr[ni], acc[mi][ni]);
  }

#pragma unroll
  for (int mi = 0; mi < 4; mi++) {
    const int row = row0 + wm * 64 + mi * 16 + quad * 4;
#pragma unroll
    for (int ni = 0; ni < 4; ni++) {
      const int col = col0 + wn * 64 + ni * 16 + l15;
#pragma unroll
      for (int r = 0; r < 4; r++) {
        const int rr = row + r;
        if constexpr (MODE == 0) {
          const bf16_t bv = (bf16_t)acc[mi][ni][r];
          if (col < 512) {
            o_q[(size_t)rr * 512 + col] = bv;
          } else if (col < 1024) {
            o_k[(size_t)rr * 512 + (col - 512)] = bv;
          } else {
            const int bb = rr >> 12;
            const int t = rr & 4095;
            o_vT[((size_t)bb * 512 + (col - 1024)) * 4096 + t] = bv;
          }
        } else {
          o_f[(size_t)rr * 512 + col] = acc[mi][ni][r];
        }
      }
    }
  }
}

// ---------------------------------------------------------------------------
// Split-KV flash attention stage 1 — counted-vmcnt raw-barrier pipeline (T3+T4).
// Block (b, s, c): 64 q-rows, 512-kv chunk, full 512-d output. Grid = 1152.
// Flat slice pipeline: slices 0..15 = K[512kv x 32d] (kt), then NV slices of
// V^T[256d x 64kv] for dh=0, then NV for dh=1 (NV = kvtmax_blk+1).
// Prefetch distance 2 into 2 x 32 KB buffers; per iteration:
//   { s_waitcnt vmcnt(8); s_barrier; compute buf[cur];
//     s_waitcnt lgkmcnt(0); s_barrier; stage slice u+2 -> buf[cur]; }
// Loads are NEVER drained to 0 in the loop (T4). Every slice is exactly 8
// global_load_lds per thread so the vmcnt literal is exact; ORDER_FENCE pins
// the prologue issue order so "oldest 16 = slices 0,1" holds.
// Phase-3 kvt fully unrolled (static pb indices — rule #20).
// Epilogue: partO in NATIVE MFMA layout -> fully coalesced 8-B stores, no
// read-modify-write at the TCC.
//   partO slice (32768 bf16 per bid):
//     flat = dh*16384 + wid*4096 + dt*256 + l15*16 + quad*4 + r
//     (q = wid*16 + quad*4 + r ; d = dh*256 + dt*16 + l15)
// ---------------------------------------------------------------------------
__global__ __launch_bounds__(256, 2) void attn_part_kernel(
    const bf16_t* __restrict__ q, const bf16_t* __restrict__ k,
    const bf16_t* __restrict__ vT, bf16_t* __restrict__ partO,
    float2* __restrict__ stats) {
  __shared__ bf16_t SB[2][16384];  // 2 x 32 KB double buffer

  const int tid = threadIdx.x;
  const int lane = tid & 63;
  const int wid = tid >> 6;
  const int quad = lane >> 4;
  const int l15 = lane & 15;

  const int bid = blockIdx.x;
  const int b = bid & 3;
  const int w = bid >> 2;  // 0..287
  int g = 0;
  while (w >= 4 * (g + 1) * (g + 2)) g++;  // strip group = s>>3
  const int rem = w - 4 * g * (g + 1);
  const int i = rem / (g + 1);
  const int c = rem - i * (g + 1);
  const int s = 8 * g + i;

  const int t0w = s * 64 + wid * 16;  // this wave's q rows
  const int kv0 = c * 512;
  const int mmax = min(31, (t0w + 15 - kv0) >> 4);         // wave-uniform
  const int kvtmax = mmax >> 2;                            // wave-uniform
  const int mmax_blk = min(31, (s * 64 + 63 - kv0) >> 4);  // block-uniform
  const int NV = (mmax_blk >> 2) + 1;                      // V slices per half
  const int NSLICE = 16 + 2 * NV;                          // >= 18 always

  const float scale = 0.044194173824159216f;  // 1/sqrt(512)
  const bf16_t* kbase = k + ((size_t)b * 4096 + kv0) * 512;
  const bf16_t* vbase = vT + ((size_t)b * 512) * 4096 + kv0;

  // stage slice u into SB[buf]; exactly 8 gload_lds16 per thread.
  auto stage_slice = [&](int u, int buf) {
    if (u < 16) {
      // K-slice [512kv x 32d], double-XOR swizzled
#pragma unroll
      for (int rnd = 0; rnd < 8; rnd++) {
        const int ch = rnd * 256 + tid;
        const int g4 = ch >> 4;
        const int w16 = ch & 15;
        const int cg = (w16 >> 2) ^ (g4 & 3);
        const int row = g4 * 4 + (w16 & 3);
        gload_lds16(kbase + (size_t)row * 512 + u * 32 + cg * 8,
                    &SB[buf][ch * 8]);
      }
    } else {
      const int v = u - 16;
      const int dh = (v >= NV) ? 1 : 0;
      const int kvt = v - dh * NV;
      const bf16_t* vb = vbase + (size_t)(dh * 256) * 4096;
      // V^T-slice [256d x 64kv], XOR swizzled
#pragma unroll
      for (int rnd = 0; rnd < 8; rnd++) {
        const int ch = rnd * 256 + tid;
        const int d = ch >> 3;
        const int cg = (ch & 7) ^ (d & 7);
        gload_lds16(vb + (size_t)d * 4096 + kvt * 64 + cg * 8, &SB[buf][ch * 8]);
      }
    }
  };

  // ---- prologue: slices 0,1 in flight (order pinned); Q frags after ------
  stage_slice(0, 0);
  ORDER_FENCE();
  stage_slice(1, 1);
  ORDER_FENCE();

  // Q B-frags: qf[kt] = Q[qrow=l15][kt*32 + quad*8 .. +7]
  bf16x8 qf[16];
  {
    const bf16_t* qp = q + ((size_t)(b * 4096 + t0w + l15)) * 512 + quad * 8;
#pragma unroll
    for (int kk = 0; kk < 16; kk++) qf[kk] = *(const bf16x8*)(qp + kk * 32);
  }

  // ---- Phase 1: S^T accumulate -------------------------------------------
  f32x4 Sacc[32];
#pragma unroll
  for (int m = 0; m < 32; m++) Sacc[m] = f32x4{0.f, 0.f, 0.f, 0.f};

  // per-lane A-frag base (elements); m-stride = 512 elements.
  const int abase =
      ((l15 >> 2) * 16 + (quad ^ ((l15 >> 2) & 3)) * 4 + (l15 & 3)) * 8;

  int cur = 0;
#pragma unroll
  for (int kt = 0; kt < 16; kt++) {
    asm volatile("s_waitcnt vmcnt(8)" ::: "memory");  // slice kt landed
    __builtin_amdgcn_sched_barrier(0);
    __builtin_amdgcn_s_barrier();
    const bf16_t* sb = &SB[cur][0];
    __builtin_amdgcn_s_setprio(1);
#pragma unroll
    for (int m = 0; m < 32; m++) {
      if (m <= mmax) {  // wave-uniform
        const bf16x8 kf = *(const bf16x8*)(sb + abase + m * 512);
        Sacc[m] = MFMA_BF16(kf, qf[kt], Sacc[m]);
      }
    }
    __builtin_amdgcn_s_setprio(0);
    asm volatile("s_waitcnt lgkmcnt(0)" ::: "memory");  // my reads done
    __builtin_amdgcn_sched_barrier(0);
    __builtin_amdgcn_s_barrier();
    stage_slice(kt + 2, cur);  // overwrite just-computed buffer (kt+2 <= 17)
    cur ^= 1;
  }

  // ---- Phase 2: masked softmax (overlaps V slices 16,17 in flight) -------
  const int qr = t0w + l15;
  float mx = NEG_BIG;
#pragma unroll
  for (int m = 0; m < 32; m++) {
    if (m <= mmax) {
#pragma unroll
      for (int r = 0; r < 4; r++) {
        const int kv = kv0 + m * 16 + quad * 4 + r;
        const float vvv = (kv <= qr) ? Sacc[m][r] : NEG_BIG;
        Sacc[m][r] = vvv;
        mx = fmaxf(mx, vvv);
      }
    }
  }
  mx = fmaxf(mx, __shfl_xor(mx, 16));
  mx = fmaxf(mx, __shfl_xor(mx, 32));  // finite: kv0 <= qr always

  float lrow = 0.0f;
  bf16x4 pb[32];
#pragma unroll
  for (int m = 0; m < 32; m++) {
    bf16x4 pv = {};
    if (m <= mmax) {
#pragma unroll
      for (int r = 0; r < 4; r++) {
        const float p = __expf((Sacc[m][r] - mx) * scale);  // masked -> 0
        pv[r] = (bf16_t)p;
        lrow += p;
      }
    }
    pb[m] = pv;
  }
  lrow += __shfl_xor(lrow, 16);
  lrow += __shfl_xor(lrow, 32);

  if (quad == 0)
    stats[((size_t)w * 4 + b) * 64 + wid * 16 + l15] =
        make_float2(mx * scale, lrow);

  // ---- Phase 3: O = P.V, both 256-d halves, unrolled kvt (rule #20) ------
  const int l64 = l15 * 64;
  const int qh = quad >> 1;
  const int ql = (quad & 1) * 4;
  const int s7 = l15 & 7;

#pragma unroll
  for (int dh = 0; dh < 2; dh++) {
    f32x4 Oacc[16];
#pragma unroll
    for (int dt = 0; dt < 16; dt++) Oacc[dt] = f32x4{0.f, 0.f, 0.f, 0.f};

#pragma unroll
    for (int kvt = 0; kvt < 8; kvt++) {
      if (kvt < NV) {  // block-uniform
        const int u = 16 + dh * NV + kvt;
        if (u < NSLICE - 1)
          asm volatile("s_waitcnt vmcnt(8)" ::: "memory");
        else
          asm volatile("s_waitcnt vmcnt(0)" ::: "memory");
        __builtin_amdgcn_sched_barrier(0);
        __builtin_amdgcn_s_barrier();
        if (kvt <= kvtmax) {  // wave-uniform
          const bf16_t* sb = &SB[cur][0];
          __builtin_amdgcn_s_setprio(1);
#pragma unroll
          for (int dt = 0; dt < 16; dt++) {
#pragma unroll
            for (int gg = 0; gg < 4; gg++) {
              const bf16x4 vf = *(const bf16x4*)(
                  sb + dt * 1024 + l64 + (((gg * 2 + qh) ^ s7) << 3) + ql);
              Oacc[dt] = mfma16(pb[kvt * 4 + gg], vf, Oacc[dt]);
            }
          }
          __builtin_amdgcn_s_setprio(0);
        }
        // epilogue on last live kvt: coalesced native-layout stores,
        // issued BEFORE the stage of u+2 so vmcnt ordering stays tight.
        if (kvt == NV - 1) {
          bf16_t* pbase =
              partO + (size_t)bid * 32768 + dh * 16384 + wid * 4096;
#pragma unroll
          for (int dt = 0; dt < 16; dt++) {
            bf16x4 ov;
#pragma unroll
            for (int r = 0; r < 4; r++) ov[r] = (bf16_t)Oacc[dt][r];
            *(bf16x4*)(pbase + dt * 256 + l15 * 16 + quad * 4) = ov;
          }
        }
        asm volatile("s_waitcnt lgkmcnt(0)" ::: "memory");
        __builtin_amdgcn_sched_barrier(0);
        __builtin_amdgcn_s_barrier();
        if (u + 2 < NSLICE) stage_slice(u + 2, cur);
        cur ^= 1;
      }
    }
  }
}

// ---------------------------------------------------------------------------
// Stage 2: combine chunk partials per (b, s); reads partO in native MFMA
// layout (coalesced), normalizes in registers, transposes through a
// row-XOR-swizzled 32 KB LDS bounce, writes coalesced bf16x8 rows.
// ---------------------------------------------------------------------------
__global__ __launch_bounds__(256) void attn_combine_kernel(
    const bf16_t* __restrict__ partO, const float2* __restrict__ stats,
    bf16_t* __restrict__ o) {
  const int b = blockIdx.x & 3;
  const int s = blockIdx.x >> 2;
  const int g = s >> 3;
  const int nc = g + 1;
  const int w0 = 4 * g * (g + 1) + (s & 7) * (g + 1);

  __shared__ float wgt[8][64];
  __shared__ float linv[64];
  __shared__ bf16_t TB[64 * 256];  // 32 KB transpose bounce

  const int tid = threadIdx.x;
  if (tid < 64) {
    float mc[8], lc[8];
    float M = NEG_BIG;
    for (int cc = 0; cc < nc; cc++) {
      const float2 ml = stats[((size_t)(w0 + cc) * 4 + b) * 64 + tid];
      mc[cc] = ml.x;
      lc[cc] = ml.y;
      M = fmaxf(M, ml.x);
    }
    float L = 0.0f;
    for (int cc = 0; cc < nc; cc++) {
      const float wv = __expf(mc[cc] - M);
      wgt[cc][tid] = wv;
      L += wv * lc[cc];
    }
    linv[tid] = (L > 0.0f) ? 1.0f / L : 0.0f;
  }
  __syncthreads();

  // thread decode matching native layout: q-rows q0..q0+3, d = dt*16 + l15
  const int quad = tid & 3;
  const int l15 = (tid >> 2) & 15;
  const int wid = tid >> 6;
  const int q0 = wid * 16 + quad * 4;
  const f32x4 li4 = *(const f32x4*)(&linv[q0]);

  for (int dh = 0; dh < 2; dh++) {
    f32x4 acc4[16] = {};
    for (int cc = 0; cc < nc; cc++) {
      const bf16_t* pp = partO + (size_t)(((w0 + cc) << 2) | b) * 32768 +
                         dh * 16384 + wid * 4096 + l15 * 16 + quad * 4;
      const f32x4 wv4 = *(const f32x4*)(&wgt[cc][q0]);
#pragma unroll
      for (int dt = 0; dt < 16; dt++) {
        const bf16x4 p = *(const bf16x4*)(pp + dt * 256);
#pragma unroll
        for (int e = 0; e < 4; e++) acc4[dt][e] += wv4[e] * (float)p[e];
      }
    }
    // normalize + swizzled bounce write ([64 q][256 d] bf16, row XOR)
#pragma unroll
    for (int dt = 0; dt < 16; dt++) {
      const int d2 = (dt * 16 + l15) * 2;
#pragma unroll
      for (int r = 0; r < 4; r++) {
        const int qq = q0 + r;
        *(bf16_t*)((char*)TB + qq * 512 + (d2 ^ ((qq & 7) << 4))) =
            (bf16_t)(acc4[dt][r] * li4[r]);
      }
    }
    __syncthreads();
    // coalesced read + store
    const int row = tid >> 2;
    const int quarter = tid & 3;
    bf16_t* orow =
        o + ((size_t)(b * 4096 + s * 64 + row)) * 512 + dh * 256 + quarter * 64;
#pragma unroll
    for (int j = 0; j < 8; j++) {
      const int byte = row * 512 + ((quarter * 128 + j * 16) ^ ((row & 7) << 4));
      *(bf16x8*)(orow + j * 8) = *(const bf16x8*)((const char*)TB + byte);
    }
    __syncthreads();  // TB reused next dh
  }
}

// ---------------------------------------------------------------------------
extern "C" void kernel_launch(void* const* d_in, const int* in_sizes, int n_in,
                              void* d_out, int out_size, void* d_ws, size_t ws_size,
                              hipStream_t stream) {
  const float* x_f = (const float*)d_in[0];   // [4,4096,512] fp32
  const float* wq_f = (const float*)d_in[1];  // [1536,512]   fp32
  const float* wp_f = (const float*)d_in[2];  // [512,512]    fp32
  float* out = (float*)d_out;                 // [4,4096,512] fp32

  // ws (bf16 unless noted): xb | wqb | wpb | q | k | vT | partO | stats
  bf16_t* xb = (bf16_t*)d_ws;                      // 16 MB (attn output)
  bf16_t* wqb = xb + (size_t)16384 * 512;          // 1.5 MB
  bf16_t* wpb = wqb + (size_t)1536 * 512;          // 0.5 MB
  bf16_t* q = wpb + (size_t)512 * 512;             // 16 MB
  bf16_t* kk = q + (size_t)16384 * 512;            // 16 MB
  bf16_t* vT = kk + (size_t)16384 * 512;           // 16 MB
  bf16_t* partO = vT + (size_t)16384 * 512;        // 1152*32768*2 = 75.5 MB
  float2* stats = (float2*)(partO + (size_t)1152 * 32768);  // 0.6 MB

  // 0) convert fp32 inputs -> bf16 (single launch)
  cvt3_kernel<<<9216, 256, 0, stream>>>(x_f, wq_f, wp_f, xb, wqb, wpb);

  // 1) qkv = x @ Wqkv^T ; v stored transposed (xb dead afterwards)
  gemm_bt_kernel<0><<<128 * 12, 256, 0, stream>>>(xb, wqb, q, kk, vT, nullptr);
  // 2a) phase-split attention partials (counted-vmcnt pipeline)
  attn_part_kernel<<<1152, 256, 0, stream>>>(q, kk, vT, partO, stats);
  // 2b) combine partials -> xb
  attn_combine_kernel<<<256, 256, 0, stream>>>(partO, stats, xb);
  // 3) y = attn @ Wproj^T -> fp32 d_out
  gemm_bt_kernel<1><<<128 * 4, 256, 0, stream>>>(xb, wpb, nullptr, nullptr, nullptr, out);
}